// Round 2
// baseline (142.070 us; speedup 1.0000x reference)
//
#include <hip/hip_runtime.h>

// Persistence-image kernel, MI355X — column-factorized variant (R2).
// S=128, I=32 intervals, C=32 corners, R=30 -> G=900.
// img[s,g] = sum_i w_i^2 * exp(-200 * max(min_c |g-b_ic|^2, min_c |g-d_ic|^2))
// |g-p|^2 = (r_c + qx_c*gx + qy_c*gy) + |g|^2 with qx=-2px, qy=-2py, r=|p|^2.
//
// R2 key change: exploit the 30x30 tensor-product grid. A thread owns ONE
// column (fixed gx) x 10 rows: per corner, p = fma(qx,gx,r) once, then each
// row is fma(qy,gy_k,p)+min -> 2.1 VALU ops/eval vs 3.0 before (-30%), and
// corner LDS reads amortize over 10 evals instead of 4.
// Grid: 2048 blocks = S x 16 (2-interval chunks), 192 threads =
// 2 interval-slots x (30 columns x 3 row-terciles) + 12 idle.
// Per-sample bbox/w^2 hoisted into a prep kernel (also zeroes out, replacing
// zero_out): main blocks lose the redundant 16KB read + shfl tree + barrier.
// Slot-1 partials combined via LDS so out gets 16 atomics/element (as before).

#define RES 30
#define GPTS 900
#define NS 128
#define NI 32
#define INV29 (1.0f / 29.0f)
#define WS_STRIDE 40  // floats per sample in ws: [0..3]=box lo/hi, [8..39]=w2[i]

__global__ __launch_bounds__(128) void prep_kernel(
    const float* __restrict__ births, const float* __restrict__ deaths,
    float* __restrict__ out, float* __restrict__ ws)
{
    const int s = blockIdx.x, tid = threadIdx.x;
    __shared__ float wc[1024];
    __shared__ float red[2][4];

    // 1024 corners/sample, 2 arrays: 512 float4 each; 4 float4/thread/array.
    const float4* b4 = (const float4*)(births + (size_t)s * 2048);
    const float4* d4 = (const float4*)(deaths + (size_t)s * 2048);
    float mnx = 3e38f, mny = 3e38f, mxx = -3e38f, mxy = -3e38f;
    #pragma unroll
    for (int k = 0; k < 4; ++k) {
        const float4 f = b4[tid + 128 * k];
        const float4 g = d4[tid + 128 * k];
        mnx = fminf(mnx, fminf(fminf(f.x, f.z), fminf(g.x, g.z)));
        mxx = fmaxf(mxx, fmaxf(fmaxf(f.x, f.z), fmaxf(g.x, g.z)));
        mny = fminf(mny, fminf(fminf(f.y, f.w), fminf(g.y, g.w)));
        mxy = fmaxf(mxy, fmaxf(fmaxf(f.y, f.w), fmaxf(g.y, g.w)));
        const int c = 2 * (tid + 128 * k);
        wc[c]     = fmaxf(fabsf(g.x - f.x), fabsf(g.y - f.y));
        wc[c + 1] = fmaxf(fabsf(g.z - f.z), fabsf(g.w - f.w));
    }
    #pragma unroll
    for (int off = 32; off > 0; off >>= 1) {
        mnx = fminf(mnx, __shfl_down(mnx, off));
        mny = fminf(mny, __shfl_down(mny, off));
        mxx = fmaxf(mxx, __shfl_down(mxx, off));
        mxy = fmaxf(mxy, __shfl_down(mxy, off));
    }
    const int wave = tid >> 6, lane = tid & 63;
    if (lane == 0) { red[wave][0] = mnx; red[wave][1] = mny; red[wave][2] = mxx; red[wave][3] = mxy; }
    __syncthreads();

    if (tid == 0) {
        const float a = fminf(red[0][0], red[1][0]);
        const float b = fminf(red[0][1], red[1][1]);
        const float c = fmaxf(red[0][2], red[1][2]);
        const float d = fmaxf(red[0][3], red[1][3]);
        const float mgx = 0.1f * (c - a), mgy = 0.1f * (d - b);
        float* w = ws + (size_t)s * WS_STRIDE;
        w[0] = a - mgx; w[1] = b - mgy; w[2] = c + mgx; w[3] = d + mgy;
    }
    if (tid < NI) {  // deterministic serial sum of 32 per-corner weights
        float ssum = 0.f;
        #pragma unroll
        for (int k = 0; k < 32; ++k) ssum += wc[tid * 32 + k];
        const float w = ssum * (1.0f / 32.0f);
        ws[(size_t)s * WS_STRIDE + 8 + tid] = w * w;
    }
    // zero this sample's output slice (replaces separate zero_out kernel;
    // kernel-node zeroing is graph-replay-safe, unlike hipMemsetAsync).
    #pragma unroll
    for (int k = 0; k < 8; ++k) {
        const int g = tid + 128 * k;
        if (g < GPTS) out[(size_t)s * GPTS + g] = 0.f;
    }
}

__global__ __launch_bounds__(192, 4) void pimg_kernel(
    const float* __restrict__ births, const float* __restrict__ deaths,
    float* __restrict__ out, const float* __restrict__ ws)
{
    const int bid = blockIdx.x;
    const int s   = bid >> 4;
    const int i0  = (bid & 15) * 2;
    const int tid = threadIdx.x;

    __shared__ __align__(16) float Bqx[64], Bqy[64], Br[64];
    __shared__ __align__(16) float Dqx[64], Dqy[64], Dr[64];
    __shared__ float sAcc[90][11];  // +1 pad: stride 11 is coprime with 32 banks

    // corner transform for this block's 2 intervals (threads 0..63)
    if (tid < 64) {
        const size_t base = (size_t)s * 1024 + (size_t)i0 * 32 + tid;
        const float2 pb = ((const float2*)births)[base];
        Bqx[tid] = -2.f * pb.x; Bqy[tid] = -2.f * pb.y; Br[tid] = pb.x * pb.x + pb.y * pb.y;
        const float2 pd = ((const float2*)deaths)[base];
        Dqx[tid] = -2.f * pd.x; Dqy[tid] = -2.f * pd.y; Dr[tid] = pd.x * pd.x + pd.y * pd.y;
    }

    // box from ws: s is block-uniform -> compiler emits scalar loads
    const float* wsp = ws + (size_t)s * WS_STRIDE;
    const float lox = wsp[0], loy = wsp[1];
    const float sx  = (wsp[2] - lox) * INV29;
    const float sy  = (wsp[3] - loy) * INV29;

    __syncthreads();

    // thread -> (interval slot ii, column ix, row-tercile h)
    const bool active = tid < 180;
    const int ii = tid / 90;        // 0..1 (2 for idle tail, never used)
    const int r  = tid - ii * 90;   // 0..89
    const int ix = r % 30;
    const int h  = r / 30;          // 0..2 -> rows [10h, 10h+10)

    float vals[10];
    if (active) {
        const float gx  = lox + (float)ix * sx;
        const float gxs = gx * gx;
        float gy[10], mb[10], md[10];
        #pragma unroll
        for (int k = 0; k < 10; ++k) {
            gy[k] = loy + (float)(10 * h + k) * sy;
            mb[k] = 3e38f; md[k] = 3e38f;
        }

        const float4* BX = (const float4*)Bqx + ii * 8;
        const float4* BY = (const float4*)Bqy + ii * 8;
        const float4* BR = (const float4*)Br  + ii * 8;
        const float4* DX = (const float4*)Dqx + ii * 8;
        const float4* DY = (const float4*)Dqy + ii * 8;
        const float4* DR = (const float4*)Dr  + ii * 8;

        #pragma unroll
        for (int q = 0; q < 8; ++q) {
            const float4 X = BX[q], Y = BY[q], R = BR[q];
            float p;
            p = fmaf(X.x, gx, R.x);
            #pragma unroll
            for (int k = 0; k < 10; ++k) mb[k] = fminf(mb[k], fmaf(Y.x, gy[k], p));
            p = fmaf(X.y, gx, R.y);
            #pragma unroll
            for (int k = 0; k < 10; ++k) mb[k] = fminf(mb[k], fmaf(Y.y, gy[k], p));
            p = fmaf(X.z, gx, R.z);
            #pragma unroll
            for (int k = 0; k < 10; ++k) mb[k] = fminf(mb[k], fmaf(Y.z, gy[k], p));
            p = fmaf(X.w, gx, R.w);
            #pragma unroll
            for (int k = 0; k < 10; ++k) mb[k] = fminf(mb[k], fmaf(Y.w, gy[k], p));
        }
        #pragma unroll
        for (int q = 0; q < 8; ++q) {
            const float4 X = DX[q], Y = DY[q], R = DR[q];
            float p;
            p = fmaf(X.x, gx, R.x);
            #pragma unroll
            for (int k = 0; k < 10; ++k) md[k] = fminf(md[k], fmaf(Y.x, gy[k], p));
            p = fmaf(X.y, gx, R.y);
            #pragma unroll
            for (int k = 0; k < 10; ++k) md[k] = fminf(md[k], fmaf(Y.y, gy[k], p));
            p = fmaf(X.z, gx, R.z);
            #pragma unroll
            for (int k = 0; k < 10; ++k) md[k] = fminf(md[k], fmaf(Y.z, gy[k], p));
            p = fmaf(X.w, gx, R.w);
            #pragma unroll
            for (int k = 0; k < 10; ++k) md[k] = fminf(md[k], fmaf(Y.w, gy[k], p));
        }

        const float w2 = ws[(size_t)s * WS_STRIDE + 8 + i0 + ii];
        #pragma unroll
        for (int k = 0; k < 10; ++k) {
            const float gg = gxs + gy[k] * gy[k];
            const float t  = fmaxf(mb[k], md[k]) + gg;
            vals[k] = w2 * __expf(-200.0f * t);
        }
    }

    // combine the two interval-slots via LDS, then one atomic per element
    if (active && ii == 1) {
        #pragma unroll
        for (int k = 0; k < 10; ++k) sAcc[r][k] = vals[k];
    }
    __syncthreads();
    if (active && ii == 0) {
        float* op = out + (size_t)s * GPTS + ix * RES + 10 * h;
        #pragma unroll
        for (int k = 0; k < 10; ++k) atomicAdd(&op[k], vals[k] + sAcc[r][k]);
    }
}

extern "C" void kernel_launch(void* const* d_in, const int* in_sizes, int n_in,
                              void* d_out, int out_size, void* d_ws, size_t ws_size,
                              hipStream_t stream) {
    const float* births = (const float*)d_in[0];
    const float* deaths = (const float*)d_in[1];
    float* out = (float*)d_out;
    float* ws  = (float*)d_ws;

    prep_kernel<<<NS, 128, 0, stream>>>(births, deaths, out, ws);
    pimg_kernel<<<NS * 16, 192, 0, stream>>>(births, deaths, out, ws);
}